// Round 7
// baseline (134.933 us; speedup 1.0000x reference)
//
#include <hip/hip_runtime.h>
#include <hip/hip_bf16.h>

// B=2, N=64, L=32, C=512, H=8, head_dim=64, NL=2048
#define NLQ 2048
#define CDIM 512
#define HD 64
#define NHEADS 8

typedef __attribute__((ext_vector_type(8))) short bf16x8;
typedef __attribute__((ext_vector_type(4))) float f32x4;

#define MFMA(A, B, Cc) __builtin_amdgcn_mfma_f32_16x16x32_bf16(A, B, Cc, 0, 0, 0)

__device__ __forceinline__ short f2bf(float x) {
    __hip_bfloat16 h = __float2bfloat16(x);
    return *reinterpret_cast<short*>(&h);
}

// Single-instruction 2^x (logits are pre-scaled by log2(e) in convert).
__device__ __forceinline__ float fast_exp2(float x) {
    float r;
    asm("v_exp_f32 %0, %1" : "=v"(r) : "v"(x));
    return r;
}

// XOR swizzle for 128-byte LDS rows (T2/G4): conflict-free column ds_read_b128.
__device__ __forceinline__ int swz(int row, int colByte) {
    return ((row << 7) + colByte) ^ ((row & 7) << 4);
}

// ws layout (bf16 elements)
#define QK_ELEMS   8388608
#define X_ELEMS    2097152
#define W_ELEMS    262144
#define PLANE      2097152

// ---------------------------------------------------------------------------
// Pass 0: fp32 -> bf16. alpha = (C^-0.5 / tau) * log2(e) folded into Wq.
// ---------------------------------------------------------------------------
__global__ __launch_bounds__(256) void convert_kernel(
    const float* __restrict__ f1, const float* __restrict__ f2,
    const float* __restrict__ Wq1, const float* __restrict__ Wk1,
    const float* __restrict__ Wq2, const float* __restrict__ Wk2,
    const float* __restrict__ tau, short* __restrict__ ws)
{
    short* Xb1 = ws + QK_ELEMS;
    short* Xb2 = Xb1 + X_ELEMS;
    short* Wb  = Xb2 + X_ELEMS;
    float la = 0.044194173824159216f * 1.4426950408889634f / tau[0];

    int bid = blockIdx.x;
    const float* src; short* dst; float a = 1.0f; int idx;
    if (bid < 1024)       { src = f1; dst = Xb1; idx = bid; }
    else if (bid < 2048)  { src = f2; dst = Xb2; idx = bid - 1024; }
    else {
        int wseg = (bid - 2048) >> 7;
        idx = (bid - 2048) & 127;
        src = (wseg == 0) ? Wq1 : (wseg == 1) ? Wk1 : (wseg == 2) ? Wq2 : Wk2;
        dst = Wb + wseg * W_ELEMS;
        a = (wseg == 0 || wseg == 2) ? la : 1.0f;
    }
    int off = idx * 2048 + threadIdx.x * 8;
    float4 x0 = *(const float4*)(src + off);
    float4 x1 = *(const float4*)(src + off + 4);
    bf16x8 v = { f2bf(x0.x * a), f2bf(x0.y * a), f2bf(x0.z * a), f2bf(x0.w * a),
                 f2bf(x1.x * a), f2bf(x1.y * a), f2bf(x1.z * a), f2bf(x1.w * a) };
    *(bf16x8*)(dst + off) = v;
}

// ---------------------------------------------------------------------------
// Pass 1: two stacked GEMMs Y = X @ [Wq;Wk]^T, 128x128 tile, BK=64, dbuf.
// A = W rows (d), B = X rows (m) -> D[d][m]: packed short4 stores along hd.
// grid: gx(2) x mt(32) x nt(8) = 512 blocks, 256 threads (2x2 waves of 64x64)
// ---------------------------------------------------------------------------
__global__ __launch_bounds__(256) void proj_kernel(short* __restrict__ ws)
{
    int bid = blockIdx.x;
    int gx = bid >> 8;          // 0: f1/(Wq1,Wk1)  1: f2/(Wq2,Wk2)
    int mt = (bid >> 3) & 31;
    int nt = bid & 7;

    const short* X   = ws + QK_ELEMS + gx * X_ELEMS;
    const short* Wst = ws + QK_ELEMS + 2 * X_ELEMS + gx * (2 * W_ELEMS); // 1024x512
    short* Yb = ws;

    __shared__ alignas(16) short Alds[2][8192];  // 128 d-rows x 64 k
    __shared__ alignas(16) short Blds[2][8192];  // 128 m-rows x 64 k

    int t = threadIdx.x;
    int lane = t & 63;
    int w = t >> 6;
    int wr = w >> 1, wc = w & 1;
    int m0 = mt * 128, d0 = nt * 128;

    int srow = t >> 1;           // 0..127
    int sh = (t & 1) * 32;       // elem offset (0 or 32) within 64-elem row
    const short* xsrc = X   + (m0 + srow) * CDIM + sh;
    const short* wsrc = Wst + (d0 + srow) * CDIM + sh;

    f32x4 acc[4][4] = {};

    bf16x8 wv0 = *(const bf16x8*)(wsrc);
    bf16x8 wv1 = *(const bf16x8*)(wsrc + 8);
    bf16x8 wv2 = *(const bf16x8*)(wsrc + 16);
    bf16x8 wv3 = *(const bf16x8*)(wsrc + 24);
    bf16x8 xv0 = *(const bf16x8*)(xsrc);
    bf16x8 xv1 = *(const bf16x8*)(xsrc + 8);
    bf16x8 xv2 = *(const bf16x8*)(xsrc + 16);
    bf16x8 xv3 = *(const bf16x8*)(xsrc + 24);
    {
        int b0 = sh * 2;
        *(bf16x8*)((char*)Alds[0] + swz(srow, b0))      = wv0;
        *(bf16x8*)((char*)Alds[0] + swz(srow, b0 + 16)) = wv1;
        *(bf16x8*)((char*)Alds[0] + swz(srow, b0 + 32)) = wv2;
        *(bf16x8*)((char*)Alds[0] + swz(srow, b0 + 48)) = wv3;
        *(bf16x8*)((char*)Blds[0] + swz(srow, b0))      = xv0;
        *(bf16x8*)((char*)Blds[0] + swz(srow, b0 + 16)) = xv1;
        *(bf16x8*)((char*)Blds[0] + swz(srow, b0 + 32)) = xv2;
        *(bf16x8*)((char*)Blds[0] + swz(srow, b0 + 48)) = xv3;
    }
    __syncthreads();

    for (int kc = 0; kc < 8; ++kc) {
        int cur = kc & 1;
        if (kc < 7) {
            const short* xn = xsrc + (kc + 1) * 64;
            const short* wn = wsrc + (kc + 1) * 64;
            wv0 = *(const bf16x8*)(wn);      wv1 = *(const bf16x8*)(wn + 8);
            wv2 = *(const bf16x8*)(wn + 16); wv3 = *(const bf16x8*)(wn + 24);
            xv0 = *(const bf16x8*)(xn);      xv1 = *(const bf16x8*)(xn + 8);
            xv2 = *(const bf16x8*)(xn + 16); xv3 = *(const bf16x8*)(xn + 24);
        }
        int cb = (lane >> 4) << 4;
        bf16x8 bfr[4][2];
        #pragma unroll
        for (int ms = 0; ms < 4; ++ms) {
            int row = (wr << 6) + (ms << 4) + (lane & 15);
            bfr[ms][0] = *(const bf16x8*)((const char*)Blds[cur] + swz(row, cb));
            bfr[ms][1] = *(const bf16x8*)((const char*)Blds[cur] + swz(row, cb + 64));
        }
        #pragma unroll
        for (int ns = 0; ns < 4; ++ns) {
            int arow = (wc << 6) + (ns << 4) + (lane & 15);
            bf16x8 a0 = *(const bf16x8*)((const char*)Alds[cur] + swz(arow, cb));
            bf16x8 a1 = *(const bf16x8*)((const char*)Alds[cur] + swz(arow, cb + 64));
            #pragma unroll
            for (int ms = 0; ms < 4; ++ms) {
                acc[ms][ns] = MFMA(a0, bfr[ms][0], acc[ms][ns]);
                acc[ms][ns] = MFMA(a1, bfr[ms][1], acc[ms][ns]);
            }
        }
        if (kc < 7) {
            int nx = cur ^ 1;
            int b0 = sh * 2;
            *(bf16x8*)((char*)Alds[nx] + swz(srow, b0))      = wv0;
            *(bf16x8*)((char*)Alds[nx] + swz(srow, b0 + 16)) = wv1;
            *(bf16x8*)((char*)Alds[nx] + swz(srow, b0 + 32)) = wv2;
            *(bf16x8*)((char*)Alds[nx] + swz(srow, b0 + 48)) = wv3;
            *(bf16x8*)((char*)Blds[nx] + swz(srow, b0))      = xv0;
            *(bf16x8*)((char*)Blds[nx] + swz(srow, b0 + 16)) = xv1;
            *(bf16x8*)((char*)Blds[nx] + swz(srow, b0 + 32)) = xv2;
            *(bf16x8*)((char*)Blds[nx] + swz(srow, b0 + 48)) = xv3;
        }
        __syncthreads();
    }

    // store: m = col (lane&15 based), d rows packed 4-wide along hd
    #pragma unroll
    for (int ms = 0; ms < 4; ++ms) {
        int m = m0 + (wr << 6) + (ms << 4) + (lane & 15);
        int bb = m >> 11, tl = m & 2047;
        #pragma unroll
        for (int ns = 0; ns < 4; ++ns) {
            int d = d0 + (wc << 6) + (ns << 4) + ((lane >> 4) << 2);
            int plane = (gx << 1) + (d >> 9);     // Q1,K1,Q2,K2 order
            int head = (d >> 6) & 7;
            int hd = d & 63;
            short4 v = { f2bf(acc[ms][ns][0]), f2bf(acc[ms][ns][1]),
                         f2bf(acc[ms][ns][2]), f2bf(acc[ms][ns][3]) };
            *(short4*)(Yb + plane * PLANE + ((bb * NHEADS + head) * NLQ + tl) * HD + hd) = v;
        }
    }
}

// ---------------------------------------------------------------------------
// Pass 2: barrier-free main loop. Waves split the KEY range (512 keys each);
// K fragments loaded directly from global (L1/L2-served), 32 MFMA : 8 loads.
// grid: qt(32) x combo(32) = 1024 blocks; bid = qt*32+combo keeps all blocks
// sharing one K matrix on the same XCD (bid%8 = combo%8).
// ---------------------------------------------------------------------------
__global__ __launch_bounds__(256) void attn_kernel(
    const short* __restrict__ qk, float* __restrict__ out)
{
    int bid = blockIdx.x;
    int combo = bid & 31;
    int qt = bid >> 5;
    int h    = combo & 7;
    int pair = (combo >> 3) & 1;
    int b    = combo >> 4;

    const short* Q = qk + (pair ? 2 : 0) * PLANE + (b * NHEADS + h) * NLQ * HD;
    const short* K = qk + (pair ? 1 : 3) * PLANE + (b * NHEADS + h) * NLQ * HD;

    __shared__ float bms[64][65];     // [key-block][q row]
    __shared__ float psums[4][64];    // [wave][q row]
    __shared__ float rowinv[64];
    __shared__ float partial[4][64];

    int t = threadIdx.x;
    int lane = t & 63;
    int w = t >> 6;

    // Q fragments: 4 q-subtiles x 2 d-halves (B-operand, col = q)
    bf16x8 qb[4][2];
    #pragma unroll
    for (int qs = 0; qs < 4; ++qs) {
        int row = qt * 64 + (qs << 4) + (lane & 15);
        const short* qp = Q + row * HD + ((lane >> 4) << 3);
        qb[qs][0] = *(const bf16x8*)qp;
        qb[qs][1] = *(const bf16x8*)(qp + 32);
    }

    float ps[4] = {0.f, 0.f, 0.f, 0.f};

    for (int i = 0; i < 8; ++i) {
        int kt = (w << 3) + i;       // this wave's 64-key tile
        int k0 = kt << 6;

        bf16x8 af[4][2];             // K fragments straight from global
        #pragma unroll
        for (int ks = 0; ks < 4; ++ks) {
            const short* kp = K + (k0 + (ks << 4) + (lane & 15)) * HD + ((lane >> 4) << 3);
            af[ks][0] = *(const bf16x8*)kp;
            af[ks][1] = *(const bf16x8*)(kp + 32);
        }

        f32x4 acc[4][4] = {};        // [ks][qs], D[key][q]
        #pragma unroll
        for (int ks = 0; ks < 4; ++ks) {
            #pragma unroll
            for (int qs = 0; qs < 4; ++qs) {
                acc[ks][qs] = MFMA(af[ks][0], qb[qs][0], acc[ks][qs]);
                acc[ks][qs] = MFMA(af[ks][1], qb[qs][1], acc[ks][qs]);
            }
        }

        #pragma unroll
        for (int qs = 0; qs < 4; ++qs) {
            // exp-sum, pairwise tree (1 serial add into ps[qs] per iter)
            float g0 = (fast_exp2(acc[0][qs][0]) + fast_exp2(acc[0][qs][1]))
                     + (fast_exp2(acc[0][qs][2]) + fast_exp2(acc[0][qs][3]));
            float g1 = (fast_exp2(acc[1][qs][0]) + fast_exp2(acc[1][qs][1]))
                     + (fast_exp2(acc[1][qs][2]) + fast_exp2(acc[1][qs][3]));
            float g2 = (fast_exp2(acc[2][qs][0]) + fast_exp2(acc[2][qs][1]))
                     + (fast_exp2(acc[2][qs][2]) + fast_exp2(acc[2][qs][3]));
            float g3 = (fast_exp2(acc[3][qs][0]) + fast_exp2(acc[3][qs][1]))
                     + (fast_exp2(acc[3][qs][2]) + fast_exp2(acc[3][qs][3]));
            ps[qs] += (g0 + g1) + (g2 + g3);

            // 32-key block maxima (max3-friendly nesting)
            float a0 = fmaxf(fmaxf(acc[0][qs][0], acc[0][qs][1]), acc[0][qs][2]);
            float a1 = fmaxf(fmaxf(acc[0][qs][3], acc[1][qs][0]), acc[1][qs][1]);
            float bm0 = fmaxf(fmaxf(a0, a1), fmaxf(acc[1][qs][2], acc[1][qs][3]));
            float a2 = fmaxf(fmaxf(acc[2][qs][0], acc[2][qs][1]), acc[2][qs][2]);
            float a3 = fmaxf(fmaxf(acc[2][qs][3], acc[3][qs][0]), acc[3][qs][1]);
            float bm1 = fmaxf(fmaxf(a2, a3), fmaxf(acc[3][qs][2], acc[3][qs][3]));

            bm0 = fmaxf(bm0, __shfl_xor(bm0, 16));
            bm0 = fmaxf(bm0, __shfl_xor(bm0, 32));
            bm1 = fmaxf(bm1, __shfl_xor(bm1, 16));
            bm1 = fmaxf(bm1, __shfl_xor(bm1, 32));
            if (lane < 16) {
                bms[2 * kt][(qs << 4) + lane]     = bm0;
                bms[2 * kt + 1][(qs << 4) + lane] = bm1;
            }
        }
    }

    // cross-wave row sums (each wave covered a disjoint 512-key slice)
    #pragma unroll
    for (int qs = 0; qs < 4; ++qs) {
        float s = ps[qs];
        s += __shfl_xor(s, 16);
        s += __shfl_xor(s, 32);
        if (lane < 16) psums[w][(qs << 4) + lane] = s;
    }
    __syncthreads();
    if (t < 64) rowinv[t] = 1.0f /
        ((psums[0][t] + psums[1][t]) + (psums[2][t] + psums[3][t]));
    __syncthreads();

    // pool exp2(blockmax)*rowinv over the 64 local q rows
    {
        int n2 = t & 63;
        int rg = t >> 6;
        float a = 0.f;
        #pragma unroll
        for (int r = rg * 16; r < rg * 16 + 16; ++r)
            a += fast_exp2(bms[n2][r]) * rowinv[r];
        partial[rg][n2] = a;
    }
    __syncthreads();

    if (t < 128) {
        int n1l = t >> 6, n2 = t & 63;
        float val = (partial[2 * n1l][n2] + partial[2 * n1l + 1][n2]) * (1.0f / 512.0f);
        atomicAdd(&out[(b * 64 + qt * 2 + n1l) * 64 + n2], val);
    }
}

extern "C" void kernel_launch(void* const* d_in, const int* in_sizes, int n_in,
                              void* d_out, int out_size, void* d_ws, size_t ws_size,
                              hipStream_t stream) {
    const float* f1  = (const float*)d_in[0];
    const float* f2  = (const float*)d_in[1];
    const float* Wq1 = (const float*)d_in[2];
    const float* Wk1 = (const float*)d_in[3];
    const float* Wq2 = (const float*)d_in[4];
    const float* Wk2 = (const float*)d_in[5];
    const float* tau = (const float*)d_in[6];
    float* out = (float*)d_out;
    short* ws = (short*)d_ws;

    hipMemsetAsync(d_out, 0, (size_t)out_size * sizeof(float), stream);
    convert_kernel<<<dim3(2560), dim3(256), 0, stream>>>(f1, f2, Wq1, Wk1, Wq2, Wk2, tau, ws);
    proj_kernel<<<dim3(512), dim3(256), 0, stream>>>(ws);
    attn_kernel<<<dim3(1024), dim3(256), 0, stream>>>(ws, out);
}